// Round 1
// baseline (37.405 us; speedup 1.0000x reference)
//
#include <hip/hip_runtime.h>

// EntityEmbedding: out[b,:] = mean_j W[x[b,j], :]
// B=16384, INPUT=50, HIDDEN=64, VOCAB=1e6, W is [VOCAB,64] f32.

#define EMB_INPUT  50
#define EMB_HIDDEN 64
#define ROWS_PER_BLOCK 16   // 256 threads / 16 lanes-per-row

__global__ __launch_bounds__(256) void emb_mean_kernel(
    const int* __restrict__ x,      // [nrows, EMB_INPUT]
    const float* __restrict__ w,    // [VOCAB, EMB_HIDDEN]
    float* __restrict__ out,        // [nrows, EMB_HIDDEN]
    int nrows)
{
    __shared__ int s_idx[ROWS_PER_BLOCK * EMB_INPUT];   // 800 ints = 3.2 KB

    const int tid = threadIdx.x;
    const int block_row0 = blockIdx.x * ROWS_PER_BLOCK;

    // Cooperative, coalesced load of this block's indices into LDS.
    const int n_idx = ROWS_PER_BLOCK * EMB_INPUT;
    const long long idx_base = (long long)block_row0 * EMB_INPUT;
    for (int i = tid; i < n_idx; i += 256) {
        long long g = idx_base + i;
        s_idx[i] = (g < (long long)nrows * EMB_INPUT) ? x[g] : 0;
    }
    __syncthreads();

    const int r = tid >> 4;     // local row 0..15
    const int t = tid & 15;     // hidden quad 0..15 -> floats [t*4, t*4+4)
    const int row = block_row0 + r;
    if (row >= nrows) return;

    const int* idx = &s_idx[r * EMB_INPUT];

    float4 acc = make_float4(0.f, 0.f, 0.f, 0.f);
    #pragma unroll 10
    for (int j = 0; j < EMB_INPUT; ++j) {
        // element offset <= 1e6*64 = 6.4e7, fits in int32
        int off = idx[j] * EMB_HIDDEN + t * 4;
        float4 v = *reinterpret_cast<const float4*>(w + off);
        acc.x += v.x; acc.y += v.y; acc.z += v.z; acc.w += v.w;
    }

    const float s = 1.0f / (float)EMB_INPUT;
    float4 o = make_float4(acc.x * s, acc.y * s, acc.z * s, acc.w * s);
    *reinterpret_cast<float4*>(out + (long long)row * EMB_HIDDEN + t * 4) = o;
}

extern "C" void kernel_launch(void* const* d_in, const int* in_sizes, int n_in,
                              void* d_out, int out_size, void* d_ws, size_t ws_size,
                              hipStream_t stream) {
    const int*   x = (const int*)d_in[0];     // [B, 50] int32
    const float* w = (const float*)d_in[1];   // [VOCAB, 64] f32
    float*     out = (float*)d_out;           // [B, 64] f32

    const int nrows = in_sizes[0] / EMB_INPUT;            // 16384
    const int grid  = (nrows + ROWS_PER_BLOCK - 1) / ROWS_PER_BLOCK;  // 1024

    emb_mean_kernel<<<grid, 256, 0, stream>>>(x, w, out, nrows);
}

// Round 2
// 35.944 us; speedup vs baseline: 1.0406x; 1.0406x over previous
//
#include <hip/hip_runtime.h>

// EntityEmbedding: out[b,:] = mean_j W[x[b,j], :]
// B=16384, INPUT=50, HIDDEN=64, VOCAB=1e6, W is [VOCAB,64] f32.
//
// One wave (64 lanes) per output row. Lane j (j<50) preloads index x[row,j];
// v_readlane broadcasts each index to SGPRs (full unroll -> constant lane),
// so each gather is global_load_dword with wave-uniform SGPR base + fixed
// per-lane voffset (lane*4): zero per-iteration VALU address math, 50
// independent 256B row loads in flight per wave.

#define EMB_INPUT  50
#define EMB_HIDDEN 64
#define WAVES_PER_BLOCK 4

__global__ __launch_bounds__(256) void emb_mean_wave_kernel(
    const int* __restrict__ x,      // [nrows, EMB_INPUT]
    const float* __restrict__ w,    // [VOCAB, EMB_HIDDEN]
    float* __restrict__ out,        // [nrows, EMB_HIDDEN]
    int nrows)
{
    const int lane = threadIdx.x & 63;
    const int wid  = threadIdx.x >> 6;
    const int row  = blockIdx.x * WAVES_PER_BLOCK + wid;
    if (row >= nrows) return;

    // Lane j holds index j of this row (lanes 50..63 hold 0, never read).
    int myidx = 0;
    if (lane < EMB_INPUT) {
        myidx = x[(long long)row * EMB_INPUT + lane];
    }

    float a0 = 0.f, a1 = 0.f, a2 = 0.f, a3 = 0.f;

    #pragma unroll
    for (int j = 0; j < EMB_INPUT; j += 2) {
        // readlane -> SGPR: wave-uniform row base, scalar address math.
        int id0 = __builtin_amdgcn_readlane(myidx, j);
        int id1 = __builtin_amdgcn_readlane(myidx, j + 1);
        const float* r0 = w + (size_t)(unsigned)id0 * EMB_HIDDEN;
        const float* r1 = w + (size_t)(unsigned)id1 * EMB_HIDDEN;
        float v0 = r0[lane];   // global_load_dword v, v_lane4, s[base0]
        float v1 = r1[lane];
        if ((j & 2) == 0) { a0 += v0; a1 += v1; }
        else              { a2 += v0; a3 += v1; }
    }

    const float s = 1.0f / (float)EMB_INPUT;
    out[(long long)row * EMB_HIDDEN + lane] = (a0 + a1 + a2 + a3) * s;
}

extern "C" void kernel_launch(void* const* d_in, const int* in_sizes, int n_in,
                              void* d_out, int out_size, void* d_ws, size_t ws_size,
                              hipStream_t stream) {
    const int*   x = (const int*)d_in[0];     // [B, 50] int32
    const float* w = (const float*)d_in[1];   // [VOCAB, 64] f32
    float*     out = (float*)d_out;           // [B, 64] f32

    const int nrows = in_sizes[0] / EMB_INPUT;                         // 16384
    const int grid  = (nrows + WAVES_PER_BLOCK - 1) / WAVES_PER_BLOCK; // 4096

    emb_mean_wave_kernel<<<grid, 256, 0, stream>>>(x, w, out, nrows);
}